// Round 11
// baseline (91.938 us; speedup 1.0000x reference)
//
#include <hip/hip_runtime.h>
#include <hip/hip_bf16.h>
#include <hip/hip_fp8.h>

typedef unsigned char u8;
typedef __attribute__((ext_vector_type(4))) float f32x4;
typedef __attribute__((ext_vector_type(4))) int   i32x4;
typedef __attribute__((ext_vector_type(8))) int   i32x8;

#define NROWS 8192   // B*N = 128*64
#define DDIM  256    // feature dim
#define NT    528    // 32*33/2 triangular 256x256 tiles

// ---------------- Kernel 1: L2-normalize rows, f32 -> fp8 e4m3 (+ zero accumulators) ----
__global__ __launch_bounds__(256) void norm_kernel(const float* __restrict__ in,
                                                   u8* __restrict__ out,
                                                   float* __restrict__ acc0) {
    int tid = threadIdx.x;
    if (blockIdx.x < 64) acc0[blockIdx.x * 256 + tid] = 0.f;  // zero tot+pos (16384 f32)
    int wave = tid >> 6, lane = tid & 63;
    int row = blockIdx.x * 4 + wave;                 // 2048 blocks * 4 rows
    float4 v = ((const float4*)(in + (size_t)row * DDIM))[lane];
    float ss = v.x * v.x + v.y * v.y + v.z * v.z + v.w * v.w;
    #pragma unroll
    for (int m = 1; m < 64; m <<= 1) ss += __shfl_xor(ss, m, 64);
    float sc = 1.0f / fmaxf(sqrtf(ss), 1e-12f);
    __hip_fp8_e4m3 q0(v.x * sc), q1(v.y * sc), q2(v.z * sc), q3(v.w * sc);
    unsigned pk = (unsigned)q0.__x | ((unsigned)q1.__x << 8) |
                  ((unsigned)q2.__x << 16) | ((unsigned)q3.__x << 24);
    ((unsigned*)out)[row * 64 + lane] = pk;          // 4 fp8 bytes per lane
}

// ---------------- Kernel 2: fused Gram + exp + row/col-sum (256x256 tiles) ----------
// 528 blocks (=8*66, XCD-chunked swizzle), one 256x256 tile each. 512 threads =
// 8 waves (2x4): wave-tile 128 rows x 64 cols (m-frags 8, n-frags 4).
// K=256 as 2 chunks of BK=128 (fp8), 128 KB dynamic-LDS double buffer:
//   STAGE(buf0,k0); STAGE(buf1,k1); vmcnt(8); barrier; compute(buf0);
//   vmcnt(0); barrier; compute(buf1); epilogue.   (no mid-loop hazards)
// MFMA: mfma_scale_f32_16x16x128_f8f6f4, unit scales (layout verified R7/R9).
// Swizzle (rule 21): linear LDS dest, inverse-swizzled source, XOR (r&7)<<4 on read.
// Epilogue 16-lane row-reduce via DPP row_shr adds (VALU pipe, zero LDS traffic).
__device__ inline void decode_tile(int k, int& ti, int& tj) {
    int a = (int)((sqrtf(8.f * (float)k + 1.f) - 1.f) * 0.5f);
    while ((a + 1) * (a + 2) / 2 <= k) ++a;
    while (a * (a + 1) / 2 > k) --a;
    ti = k - a * (a + 1) / 2;  // row tile
    tj = a;                    // col tile, ti <= tj
}

__device__ inline float dpp_shr_add(float x, const int stage) {
    // x += (lane >= N within 16-row ? lane-N's x : 0);  stage: 0x111/0x112/0x114/0x118
    int y;
    if      (stage == 1) y = __builtin_amdgcn_update_dpp(0, __float_as_int(x), 0x111, 0xf, 0xf, true);
    else if (stage == 2) y = __builtin_amdgcn_update_dpp(0, __float_as_int(x), 0x112, 0xf, 0xf, true);
    else if (stage == 4) y = __builtin_amdgcn_update_dpp(0, __float_as_int(x), 0x114, 0xf, 0xf, true);
    else                 y = __builtin_amdgcn_update_dpp(0, __float_as_int(x), 0x118, 0xf, 0xf, true);
    return x + __int_as_float(y);
}

__global__ __launch_bounds__(512, 2) void sim_kernel(const u8* __restrict__ f8,
                                                     float* __restrict__ tot_acc,
                                                     float* __restrict__ pos_acc) {
    extern __shared__ u8 lds[];        // 128 KB: [buf0 A|B][buf1 A|B], 32 KB each
    u8* const lA0 = lds;
    u8* const lB0 = lds + 32768;
    u8* const lA1 = lds + 65536;
    u8* const lB1 = lds + 98304;

    const int tid  = threadIdx.x;
    const int lane = tid & 63;
    const int wave = tid >> 6;         // 0..7
    const int wr = wave >> 2;          // 0..1 : rows wr*128 .. +127
    const int wc = wave & 3;           // 0..3 : cols wc*64  .. +63

    int k = (blockIdx.x & 7) * 66 + (blockIdx.x >> 3);   // XCD-chunked (528 = 8*66)
    int ti, tj;
    decode_tile(k, ti, tj);
    const int brow = ti * 256, bcol = tj * 256;

    // stage one K-chunk: 8 glds(16B)/thread (4 A + 4 B); panels [256 rows][128 B]
    #define STAGE(pA, pB, kc)                                                        \
        {                                                                            \
            _Pragma("unroll")                                                        \
            for (int i = 0; i < 4; ++i) {                                            \
                int o   = (i * 512 + tid) * 16;   /* linear LDS byte offset */       \
                int r   = o >> 7;                 /* row (128 B per row) */          \
                int cb  = o & 127;                                                   \
                int scb = cb ^ ((r & 7) << 4);    /* inverse-swizzled source */      \
                const u8* gA = f8 + (size_t)(brow + r) * DDIM + (kc) + scb;          \
                __builtin_amdgcn_global_load_lds(                                    \
                    (const __attribute__((address_space(1))) void*)gA,               \
                    (__attribute__((address_space(3))) void*)((pA) + o), 16, 0, 0);  \
                const u8* gB = f8 + (size_t)(bcol + r) * DDIM + (kc) + scb;          \
                __builtin_amdgcn_global_load_lds(                                    \
                    (const __attribute__((address_space(1))) void*)gB,               \
                    (__attribute__((address_space(3))) void*)((pB) + o), 16, 0, 0);  \
            }                                                                        \
        }

    f32x4 acc[8][4];
    #pragma unroll
    for (int m = 0; m < 8; ++m)
        #pragma unroll
        for (int n = 0; n < 4; ++n)
            acc[m][n] = (f32x4){0.f, 0.f, 0.f, 0.f};

    STAGE(lA0, lB0, 0);
    STAGE(lA1, lB1, 128);

    const int kb = (lane >> 4) << 5;   // this lane-group's 32 k-bytes start

    // compute one chunk: 24 ds_read_b128 + 32 MX MFMAs per wave
    #define COMPUTE(bA, bB)                                                          \
        {                                                                            \
            i32x8 bv[4];                                                             \
            _Pragma("unroll")                                                        \
            for (int n = 0; n < 4; ++n) {                                            \
                int rB = wc * 64 + n * 16 + (lane & 15);                             \
                int sw = (rB & 7) << 4;                                              \
                const u8* p = (bB) + rB * 128;                                       \
                i32x4 lo = *(const i32x4*)(p + (kb ^ sw));                           \
                i32x4 hi = *(const i32x4*)(p + ((kb + 16) ^ sw));                    \
                bv[n][0] = lo[0]; bv[n][1] = lo[1]; bv[n][2] = lo[2]; bv[n][3] = lo[3]; \
                bv[n][4] = hi[0]; bv[n][5] = hi[1]; bv[n][6] = hi[2]; bv[n][7] = hi[3]; \
            }                                                                        \
            _Pragma("unroll")                                                        \
            for (int m = 0; m < 8; ++m) {                                            \
                int rA = wr * 128 + m * 16 + (lane & 15);                            \
                int sw = (rA & 7) << 4;                                              \
                const u8* p = (bA) + rA * 128;                                       \
                i32x4 lo = *(const i32x4*)(p + (kb ^ sw));                           \
                i32x4 hi = *(const i32x4*)(p + ((kb + 16) ^ sw));                    \
                i32x8 av;                                                            \
                av[0] = lo[0]; av[1] = lo[1]; av[2] = lo[2]; av[3] = lo[3];          \
                av[4] = hi[0]; av[5] = hi[1]; av[6] = hi[2]; av[7] = hi[3];          \
                _Pragma("unroll")                                                    \
                for (int n = 0; n < 4; ++n)                                          \
                    acc[m][n] = __builtin_amdgcn_mfma_scale_f32_16x16x128_f8f6f4(    \
                        av, bv[n], acc[m][n], 0, 0, 0, 0x7f7f7f7f, 0, 0x7f7f7f7f);   \
            }                                                                        \
        }

    asm volatile("s_waitcnt vmcnt(8)" ::: "memory");   // chunk0 landed; chunk1 in flight
    __builtin_amdgcn_s_barrier();
    COMPUTE(lA0, lB0);
    asm volatile("s_waitcnt vmcnt(0)" ::: "memory");   // chunk1 landed
    __builtin_amdgcn_s_barrier();
    COMPUTE(lA1, lB1);
    #undef STAGE
    #undef COMPUTE

    // ---- epilogue ----
    // C layout: col = lane&15 (+n*16), row = (lane>>4)*4 + j (+m*16)  [verified R7/R9]
    #pragma unroll
    for (int m = 0; m < 8; ++m)
        #pragma unroll
        for (int n = 0; n < 4; ++n)
            #pragma unroll
            for (int j = 0; j < 4; ++j)
                acc[m][n][j] = __expf(acc[m][n][j]);

    // row partial sums over this wave's 64 cols: in-reg n-sum, then DPP 16-lane reduce
    float rs[8][4];
    #pragma unroll
    for (int m = 0; m < 8; ++m) {
        f32x4 s = acc[m][0] + acc[m][1] + acc[m][2] + acc[m][3];
        #pragma unroll
        for (int j = 0; j < 4; ++j) {
            float v = s[j];
            v = dpp_shr_add(v, 1);
            v = dpp_shr_add(v, 2);
            v = dpp_shr_add(v, 4);
            v = dpp_shr_add(v, 8);   // lane c==15 of each 16-group holds the sum
            rs[m][j] = v;
        }
    }

    const int g = lane >> 4;
    const int colbatch = tj * 4 + wc;                 // cols wc*64.. = one 64-batch
    if ((lane & 15) == 15) {
        #pragma unroll
        for (int m = 0; m < 8; ++m) {
            const bool diag = (ti * 4 + wr * 2 + (m >> 2)) == colbatch;  // wave-uniform/m
            #pragma unroll
            for (int j = 0; j < 4; ++j) {
                int row = brow + wr * 128 + m * 16 + g * 4 + j;
                atomicAdd(&tot_acc[row], rs[m][j]);
                if (diag) atomicAdd(&pos_acc[row], rs[m][j]);
            }
        }
    }

    if (ti != tj) {   // transpose contribution: col sums -> tot of the col rows
        float cs[4];
        #pragma unroll
        for (int n = 0; n < 4; ++n) {
            f32x4 t = acc[0][n];
            #pragma unroll
            for (int m = 1; m < 8; ++m) t = t + acc[m][n];
            float s = t[0] + t[1] + t[2] + t[3];
            s += __shfl_xor(s, 16, 64);
            s += __shfl_xor(s, 32, 64);
            cs[n] = s;
        }
        if (lane < 16) {
            #pragma unroll
            for (int n = 0; n < 4; ++n)
                atomicAdd(&tot_acc[bcol + wc * 64 + n * 16 + lane], cs[n]);
        }
    }
}

// ---------------- Kernel 3: loss = mean(log(total) - log(pos)) ----------------
__global__ __launch_bounds__(1024) void loss_kernel(const float* __restrict__ tot,
                                                    const float* __restrict__ pos,
                                                    float* __restrict__ out) {
    __shared__ float red[16];
    int tid = threadIdx.x;
    float s = 0.f;
    for (int r = tid; r < NROWS; r += 1024)
        s += logf(tot[r]) - logf(pos[r]);
    #pragma unroll
    for (int m = 1; m < 64; m <<= 1) s += __shfl_xor(s, m, 64);
    if ((tid & 63) == 0) red[tid >> 6] = s;
    __syncthreads();
    if (tid == 0) {
        float t = 0.f;
        #pragma unroll
        for (int i = 0; i < 16; ++i) t += red[i];
        out[0] = t * (1.0f / (float)NROWS);
    }
}

extern "C" void kernel_launch(void* const* d_in, const int* in_sizes, int n_in,
                              void* d_out, int out_size, void* d_ws, size_t ws_size,
                              hipStream_t stream) {
    const float* feat = (const float*)d_in[0];
    u8*    f8   = (u8*)d_ws;                                    // 8192*256 = 2 MB
    float* tot  = (float*)((char*)d_ws + (size_t)NROWS * DDIM); // +2 MB
    float* pos  = tot + NROWS;
    hipFuncSetAttribute(reinterpret_cast<const void*>(sim_kernel),
                        hipFuncAttributeMaxDynamicSharedMemorySize, 131072);
    norm_kernel<<<dim3(NROWS / 4), dim3(256), 0, stream>>>(feat, f8, tot);
    sim_kernel<<<dim3(NT), dim3(512), 131072, stream>>>(f8, tot, pos);
    loss_kernel<<<dim3(1), dim3(1024), 0, stream>>>(tot, pos, (float*)d_out);
}